// Round 2
// baseline (357.551 us; speedup 1.0000x reference)
//
#include <hip/hip_runtime.h>
#include <stdint.h>

// PixCorr R7: drop LDS staging entirely.
// Post-mortem of R4/R5/R6: three different staging structures (VGPR batch,
// global_load_lds + drain, global_load_lds + counted-vmcnt deep pipeline) all
// converge at ~3.5-3.8 TB/s, while the harness's own fill runs 6.7 TB/s and
// the guide's measured read-side references (LN 82%, RMSNorm 86% of HBM BW)
// are plain vectorized VGPR loads at MAX OCCUPANCY with no LDS. This kernel
// has zero reuse -> LDS staging buys nothing and costs occupancy (8 waves/CU
// from 32-64KiB LDS blocks). R7: LDS-free streaming, 2048 blocks x 256 thr
// (32 waves/CU at <=64 VGPR -> full 8192-wave residency), nontemporal float4
// loads, 2-deep register double-buffer, fp64 accumulate, block reduce.

typedef float f4 __attribute__((ext_vector_type(4)));

constexpr int    NROWS   = 256;
constexpr int    D       = 3 * 256 * 256;     // 196608 floats per row
constexpr int    D4      = D / 4;             // 49152 float4 per row
constexpr int    BPR     = 8;                 // blocks per row
constexpr int    NBLOCKS = NROWS * BPR;       // 2048
constexpr int    TPB     = 256;               // 4 waves
constexpr int    SPAN    = D4 / BPR;          // 6144 float4 per block per array
constexpr int    ITER    = SPAN / TPB;        // 24 float4-pairs per thread
constexpr double EPS     = 1e-6;

// partials layout: [block][5] doubles = 2048*5 (80 KiB), order {sZ,sB,sZZ,sBB,sZB}.
__global__ __launch_bounds__(TPB) void partial_kernel(
        const f4* __restrict__ preds,
        const f4* __restrict__ targets,
        double* __restrict__ partials)
{
    const int  tid  = threadIdx.x;
    const int  blk  = blockIdx.x;
    const int  row  = blk >> 3;          // blk / BPR
    const int  oct  = blk & (BPR - 1);
    const long base = (long)row * D4 + (long)oct * SPAN + tid;

    double sZ = 0, sB = 0, sZZ = 0, sBB = 0, sZB = 0;

    // b = preds, z = targets (matches reference naming).
    auto accum = [&](const f4 bv, const f4 zv) {
        #pragma unroll
        for (int c = 0; c < 4; ++c) {
            const double b = (double)bv[c];
            const double z = (double)zv[c];
            sZ += z; sB += b;
            sZZ = fma(z, z, sZZ);
            sBB = fma(b, b, sBB);
            sZB = fma(z, b, sZB);
        }
    };

    // 2-deep register double-buffer; #pragma unroll 1 keeps the unroller from
    // hoisting all 48 loads (VGPR blowup). TLP (32 waves/CU) does the latency
    // hiding; per-wave ILP of 4-8 outstanding dwordx4 is gravy.
    f4 pc0 = __builtin_nontemporal_load(&preds[base]);
    f4 pc1 = __builtin_nontemporal_load(&preds[base + TPB]);
    f4 tc0 = __builtin_nontemporal_load(&targets[base]);
    f4 tc1 = __builtin_nontemporal_load(&targets[base + TPB]);

    #pragma unroll 1
    for (int i = 0; i < ITER - 2; i += 2) {
        const long nb = base + (long)(i + 2) * TPB;
        const f4 pn0 = __builtin_nontemporal_load(&preds[nb]);
        const f4 pn1 = __builtin_nontemporal_load(&preds[nb + TPB]);
        const f4 tn0 = __builtin_nontemporal_load(&targets[nb]);
        const f4 tn1 = __builtin_nontemporal_load(&targets[nb + TPB]);
        accum(pc0, tc0);
        accum(pc1, tc1);
        pc0 = pn0; pc1 = pn1; tc0 = tn0; tc1 = tn1;
    }
    accum(pc0, tc0);
    accum(pc1, tc1);

    // Wave (64-lane) shuffle reduction.
    #pragma unroll
    for (int off = 32; off > 0; off >>= 1) {
        sZ  += __shfl_down(sZ,  off);
        sB  += __shfl_down(sB,  off);
        sZZ += __shfl_down(sZZ, off);
        sBB += __shfl_down(sBB, off);
        sZB += __shfl_down(sZB, off);
    }

    constexpr int NWAVES = TPB / 64;
    __shared__ double sm[5][NWAVES];
    const int w    = tid >> 6;
    const int lane = tid & 63;
    if (lane == 0) {
        sm[0][w] = sZ;  sm[1][w] = sB;
        sm[2][w] = sZZ; sm[3][w] = sBB;
        sm[4][w] = sZB;
    }
    __syncthreads();
    if (tid == 0) {
        double* o = partials + (long)blk * 5;
        #pragma unroll
        for (int k = 0; k < 5; ++k)
            o[k] = sm[k][0] + sm[k][1] + sm[k][2] + sm[k][3];
    }
}

// One thread per row: sum its 8 block-partials (40 contiguous doubles),
// compute the row correlation, block-reduce the mean. Single launch.
__global__ __launch_bounds__(NROWS) void finalize_kernel(
        const double* __restrict__ partials, float* __restrict__ out)
{
    const int r = threadIdx.x;
    const double* p = partials + (long)r * BPR * 5;
    double tZ = 0, tB = 0, tZZ = 0, tBB = 0, tZB = 0;
    #pragma unroll
    for (int s = 0; s < BPR; ++s) {
        tZ  += p[s * 5 + 0];
        tB  += p[s * 5 + 1];
        tZZ += p[s * 5 + 2];
        tBB += p[s * 5 + 3];
        tZB += p[s * 5 + 4];
    }
    const double invD = 1.0 / (double)D;
    const double num  = tZB - tZ * tB * invD;
    const double varZ = fmax(tZZ - tZ * tZ * invD, 0.0);
    const double varB = fmax(tBB - tB * tB * invD, 0.0);
    const double den  = sqrt(varZ) * sqrt(varB) + EPS;
    double corr = num / den;

    #pragma unroll
    for (int off = 32; off > 0; off >>= 1) corr += __shfl_down(corr, off);

    __shared__ double sm[NROWS / 64];
    const int wave = r >> 6;
    const int lane = r & 63;
    if (lane == 0) sm[wave] = corr;
    __syncthreads();
    if (r == 0) {
        double t = 0.0;
        #pragma unroll
        for (int v = 0; v < NROWS / 64; ++v) t += sm[v];
        out[0] = (float)(t / (double)NROWS);
    }
}

extern "C" void kernel_launch(void* const* d_in, const int* in_sizes, int n_in,
                              void* d_out, int out_size, void* d_ws, size_t ws_size,
                              hipStream_t stream) {
    const f4* preds   = (const f4*)d_in[0];
    const f4* targets = (const f4*)d_in[1];
    double* partials  = (double*)d_ws;     // 2048*5 doubles = 80 KiB
    float*  out       = (float*)d_out;

    hipLaunchKernelGGL(partial_kernel, dim3(NBLOCKS), dim3(TPB), 0, stream,
                       preds, targets, partials);
    hipLaunchKernelGGL(finalize_kernel, dim3(1), dim3(NROWS), 0, stream,
                       partials, out);
}